// Round 7
// baseline (125.504 us; speedup 1.0000x reference)
//
#include <hip/hip_runtime.h>
#include <hip/hip_bf16.h>
#include <math.h>

#define B_ 8
#define N_ 256
#define H_ 128
#define NODES_ (B_ * N_)   // 2048

__device__ __forceinline__ float silu_fast(float x) {
    float e = __expf(-x);
    return x * __builtin_amdgcn_rcpf(1.0f + e);
}

// K=128 column-GEMM: thread owns 4 output columns (Wc pre-offset by c0, row
// stride H_); activations arow[] in LDS (wave-broadcast reads).
// FLAT unroll-8 loop: compiler clumps independent float4 loads per window
// and schedules waitcnt itself. Allocator-safe (R4/R5 lesson: manual deep
// ping-pong spilled: VGPR=256, 100+ MB scratch traffic).
__device__ __forceinline__ float4 cg128(const float* __restrict__ Wc,
                                        const float* __restrict__ arow)
{
    float4 acc = {0.f, 0.f, 0.f, 0.f};
    #pragma unroll 8
    for (int k = 0; k < 128; ++k) {
        float4 w = *(const float4*)(Wc + k * H_);
        float v  = arow[k];
        acc.x = fmaf(v, w.x, acc.x);
        acc.y = fmaf(v, w.y, acc.y);
        acc.z = fmaf(v, w.z, acc.z);
        acc.w = fmaf(v, w.w, acc.w);
    }
    return acc;
}

// ---------------------------------------------------------------------------
// k1: g=0: P = node@We1a + be1
//     g=1: Q = node@We1b + (m_j-1)*1e30   (mask_j folded: silu -> -0)
//     g=2: pre = node@Wn1a + bn1
// grid 768, block 256: 8 nodes/block, n = t>>5, c0 = (t&31)*4.
// ---------------------------------------------------------------------------
__global__ __launch_bounds__(256) void k1(
    const float* __restrict__ node, const float* __restrict__ We1,
    const float* __restrict__ be1, const float* __restrict__ Wn1,
    const float* __restrict__ bn1, const float* __restrict__ mask,
    float* __restrict__ P, float* __restrict__ Q, float* __restrict__ pre)
{
    __shared__ float act[8][128];
    const int t = threadIdx.x;
    const int g = blockIdx.x >> 8;               // 0:P 1:Q 2:pre
    const int node0 = (blockIdx.x & 255) * 8;
    {
        int idx = t * 4;
        int r = idx >> 7, col = idx & 127;
        *(float4*)(&act[r][col]) = *(const float4*)(node + (size_t)(node0 + r) * H_ + col);
    }
    const float* W; float* op;
    if (g == 0)      { W = We1;            op = P;   }
    else if (g == 1) { W = We1 + 128 * H_; op = Q;   }
    else             { W = Wn1;            op = pre; }
    const int n  = t >> 5;
    const int c0 = (t & 31) * 4;
    __syncthreads();

    float4 r4 = cg128(W + c0, &act[n][0]);
    if (g == 0) {
        float4 bv = *(const float4*)(be1 + c0);
        r4.x += bv.x; r4.y += bv.y; r4.z += bv.z; r4.w += bv.w;
    } else if (g == 1) {
        float off = (mask[node0 + n] - 1.0f) * 1e30f;   // 0 if m=1, -1e30 if m=0
        r4.x += off; r4.y += off; r4.z += off; r4.w += off;
    } else {
        float4 bv = *(const float4*)(bn1 + c0);
        r4.x += bv.x; r4.y += bv.y; r4.z += bv.z; r4.w += bv.w;
    }
    *(float4*)(op + (size_t)(node0 + n) * H_ + c0) = r4;
}

// ---------------------------------------------------------------------------
// k2 (v2, LDS-staged): S'[i][c] = (m_i/max(cnt,1)) * sum_j silu(P[i][c] +
//   Q'[j][c] + d_ij*wd[c]);  mask_j folded into Q' (silu -> -0).
// grid 512 (4 i/block), block 512: thread = (i = t>>7, c = t&127) owns ONE
// output accumulator — no cross-thread reduction. j processed in 4 chunks of
// 64; each chunk's Q slice (32 KB) staged to LDS via coalesced float4 loads,
// register-prefetched one chunk ahead. Inner loop: 2 LDS b32 (q: stride-1
// banks; d: broadcast) + 5 full-rate VALU + exp + rcp -> trans-pipe-bound.
// ---------------------------------------------------------------------------
__global__ __launch_bounds__(512) void k2(
    const float* __restrict__ P, const float* __restrict__ Q,
    const float* __restrict__ We1, const float* __restrict__ positions,
    const float* __restrict__ mask, float* __restrict__ S)
{
    __shared__ float Qs[64 * 128];    // 32 KB: one 64-j chunk
    __shared__ float dls[256][4];     // dist[j][i]
    __shared__ float cs;
    const int t  = threadIdx.x;
    const int b  = blockIdx.x >> 6;
    const int i0 = (blockIdx.x & 63) * 4;

    // pairwise distances for this block's 4 i-rows
    {
        const int t2 = t & 255;
        const int half = t >> 8;
        const int il = t2 & 3;
        const int jb = t2 >> 2;
        const float* pb = positions + b * N_ * 3;
        const float pix = pb[(i0 + il) * 3 + 0];
        const float piy = pb[(i0 + il) * 3 + 1];
        const float piz = pb[(i0 + il) * 3 + 2];
        #pragma unroll
        for (int s = 0; s < 2; ++s) {
            int j = jb + 64 * (half * 2 + s);
            float dx = pix - pb[j * 3 + 0];
            float dy = piy - pb[j * 3 + 1];
            float dz = piz - pb[j * 3 + 2];
            float sq = dx * dx + dy * dy + dz * dz;
            dls[j][il] = (sq > 0.f) ? sqrtf(sq) : 0.f;
        }
    }
    if (t < 64) {   // cnt = sum_j mask[b][j]
        float mv = mask[b * N_ + t] + mask[b * N_ + 64 + t]
                 + mask[b * N_ + 128 + t] + mask[b * N_ + 192 + t];
        #pragma unroll
        for (int off = 32; off >= 1; off >>= 1) mv += __shfl_down(mv, off);
        if (t == 0) cs = mv;
    }

    const int i = t >> 7;             // wave-uniform
    const int c = t & 127;
    const float wd   = We1[256 * H_ + c];
    const float base = P[(size_t)(b * N_ + i0 + i) * H_ + c];
    const float4* __restrict__ Qg = (const float4*)(Q + (size_t)(b * N_) * H_);

    // prefetch chunk 0 into registers (4 float4/thread = one 32 KB chunk/block)
    float4 r0 = Qg[0 * 2048 + 0 * 512 + t];
    float4 r1 = Qg[0 * 2048 + 1 * 512 + t];
    float4 r2 = Qg[0 * 2048 + 2 * 512 + t];
    float4 r3 = Qg[0 * 2048 + 3 * 512 + t];

    float acc = 0.f;
    for (int ch = 0; ch < 4; ++ch) {
        __syncthreads();              // previous chunk's compute done
        ((float4*)Qs)[0 * 512 + t] = r0;
        ((float4*)Qs)[1 * 512 + t] = r1;
        ((float4*)Qs)[2 * 512 + t] = r2;
        ((float4*)Qs)[3 * 512 + t] = r3;
        if (ch < 3) {                 // prefetch next chunk; lands during compute
            r0 = Qg[(ch + 1) * 2048 + 0 * 512 + t];
            r1 = Qg[(ch + 1) * 2048 + 1 * 512 + t];
            r2 = Qg[(ch + 1) * 2048 + 2 * 512 + t];
            r3 = Qg[(ch + 1) * 2048 + 3 * 512 + t];
        }
        __syncthreads();              // staging visible
        const int j0 = ch * 64;
        #pragma unroll 8
        for (int jj = 0; jj < 64; ++jj) {
            float q = Qs[jj * 128 + c];
            float d = dls[j0 + jj][i];
            float x = fmaf(d, wd, base + q);
            float e = __expf(-x);
            float r = __builtin_amdgcn_rcpf(1.0f + e);
            acc = fmaf(x, r, acc);    // silu = x*sigmoid; masked j: x~-1e30, r=0 -> -0
        }
    }

    const float inv_cnt = __builtin_amdgcn_rcpf(fmaxf(cs, 1.0f));
    const float mi = mask[b * N_ + i0 + i];
    S[(size_t)(b * N_ + i0 + i) * H_ + c] = (mi * inv_cnt) * acc;
}

// ---------------------------------------------------------------------------
// kBC: fused node epilogue, 3 chained GEMMs through LDS:
//   T      = S' @ We2 + m_i*be2          (be2 fold: (T+mi*be2)@Wn1b ==
//   hidden = silu(pre + T @ Wn1[128:])    T@Wn1b + mi*(be2@Wn1b))
//   out    = node + m_i * (hidden @ Wn2 + bn2)
// grid 512 (4 nodes/block), block 128: n = t>>5, c0 = (t&31)*4.
// ---------------------------------------------------------------------------
__global__ __launch_bounds__(128) void kBC(
    const float* __restrict__ S, const float* __restrict__ pre,
    const float* __restrict__ node, const float* __restrict__ mask,
    const float* __restrict__ We2, const float* __restrict__ be2,
    const float* __restrict__ Wn1, const float* __restrict__ Wn2,
    const float* __restrict__ bn2, float* __restrict__ out)
{
    __shared__ float A[4][128], T[4][128];
    const int t = threadIdx.x;
    const int node0 = blockIdx.x * 4;
    {
        int idx = t * 4;
        int r = idx >> 7, col = idx & 127;
        *(float4*)(&A[r][col]) = *(const float4*)(S + (size_t)(node0 + r) * H_ + col);
    }
    const int n  = t >> 5;
    const int c0 = (t & 31) * 4;
    const float mi = mask[node0 + n];
    __syncthreads();

    // phase 1: T = S' @ We2 + mi*be2
    float4 x = cg128(We2 + c0, &A[n][0]);
    {
        float4 b2 = *(const float4*)(be2 + c0);
        x.x = fmaf(mi, b2.x, x.x); x.y = fmaf(mi, b2.y, x.y);
        x.z = fmaf(mi, b2.z, x.z); x.w = fmaf(mi, b2.w, x.w);
    }
    *(float4*)(&T[n][c0]) = x;
    __syncthreads();

    // phase 2: hidden = silu(pre + T @ Wn1b)
    float4 y = cg128(Wn1 + 128 * H_ + c0, &T[n][0]);
    float4 p4 = *(const float4*)(pre + (size_t)(node0 + n) * H_ + c0);
    float4 h;
    h.x = silu_fast(p4.x + y.x);
    h.y = silu_fast(p4.y + y.y);
    h.z = silu_fast(p4.z + y.z);
    h.w = silu_fast(p4.w + y.w);
    *(float4*)(&A[n][c0]) = h;
    __syncthreads();

    // phase 3: out = node + mi * (hidden @ Wn2 + bn2)
    float4 z = cg128(Wn2 + c0, &A[n][0]);
    float4 n4 = *(const float4*)(node + (size_t)(node0 + n) * H_ + c0);
    float4 bv = *(const float4*)(bn2 + c0);
    float4 r4;
    r4.x = n4.x + mi * (z.x + bv.x);
    r4.y = n4.y + mi * (z.y + bv.y);
    r4.z = n4.z + mi * (z.z + bv.z);
    r4.w = n4.w + mi * (z.w + bv.w);
    *(float4*)(out + (size_t)(node0 + n) * H_ + c0) = r4;
}

extern "C" void kernel_launch(void* const* d_in, const int* in_sizes, int n_in,
                              void* d_out, int out_size, void* d_ws, size_t ws_size,
                              hipStream_t stream)
{
    const float* node      = (const float*)d_in[0];
    const float* positions = (const float*)d_in[1];
    const float* mask      = (const float*)d_in[2];
    const float* We1       = (const float*)d_in[3];
    const float* be1       = (const float*)d_in[4];
    const float* We2       = (const float*)d_in[5];
    const float* be2       = (const float*)d_in[6];
    const float* Wn1       = (const float*)d_in[7];
    const float* bn1       = (const float*)d_in[8];
    const float* Wn2       = (const float*)d_in[9];
    const float* bn2       = (const float*)d_in[10];
    float* out = (float*)d_out;

    const size_t SZ = (size_t)NODES_ * H_;     // 1 MB each
    float* P   = (float*)d_ws;
    float* Q   = P + SZ;
    float* pre = Q + SZ;
    float* S   = pre + SZ;                     // peak ws = 4 MB

    k1 <<<768, 256, 0, stream>>>(node, We1, be1, Wn1, bn1, mask, P, Q, pre);
    k2 <<<512, 512, 0, stream>>>(P, Q, We1, positions, mask, S);
    kBC<<<512, 128, 0, stream>>>(S, pre, node, mask, We2, be2, Wn1, Wn2, bn2, out);
}

// Round 8
// 103.304 us; speedup vs baseline: 1.2149x; 1.2149x over previous
//
#include <hip/hip_runtime.h>
#include <hip/hip_bf16.h>
#include <math.h>

#define B_ 8
#define N_ 256
#define H_ 128
#define NODES_ (B_ * N_)   // 2048

__device__ __forceinline__ float silu_fast(float x) {
    float e = __expf(-x);
    return x * __builtin_amdgcn_rcpf(1.0f + e);
}

// ---------------------------------------------------------------------------
// k1 (split-K): g=0: P = node@We1a + be1
//               g=1: Q = node@We1b + (m_j-1)*1e30   (mask_j folded: silu -> -0)
//               g=2: pre = node@Wn1a + bn1
// grid 1536 = 3 gemms x 512 tiles (4 nodes), block 512.
// thread = (kseg = t>>5: 8 k's, c0 = (t&31)*4): each weight float4 loaded by
// EXACTLY ONE thread (no L2 amplification — R7 lesson: col-owner layout had
// 8x amplification = 384 MB L2 traffic), reused across 4 nodes in registers.
// 16-way k-segment reduce through LDS.
// ---------------------------------------------------------------------------
__global__ __launch_bounds__(512) void k1(
    const float* __restrict__ node, const float* __restrict__ We1,
    const float* __restrict__ be1, const float* __restrict__ Wn1,
    const float* __restrict__ bn1, const float* __restrict__ mask,
    float* __restrict__ P, float* __restrict__ Q, float* __restrict__ pre)
{
    __shared__ float act[4][128];
    __shared__ float pls[16][4][128];   // partials [kseg][n][c]
    const int t = threadIdx.x;
    const int g = blockIdx.x >> 9;
    const int node0 = (blockIdx.x & 511) * 4;

    if (t < 128) {
        int r = t >> 5, col = (t & 31) * 4;
        *(float4*)(&act[r][col]) = *(const float4*)(node + (size_t)(node0 + r) * H_ + col);
    }
    const float* W = (g == 0) ? We1 : (g == 1) ? (We1 + 128 * H_) : Wn1;
    const int kseg = t >> 5;
    const int c0   = (t & 31) * 4;
    __syncthreads();

    float4 w[8];
    const float* Wb = W + (size_t)(kseg * 8) * H_ + c0;
    #pragma unroll
    for (int u = 0; u < 8; ++u) w[u] = *(const float4*)(Wb + u * H_);

    #pragma unroll
    for (int n = 0; n < 4; ++n) {
        float4 a = {0.f, 0.f, 0.f, 0.f};
        #pragma unroll
        for (int u = 0; u < 8; ++u) {
            float v = act[n][kseg * 8 + u];      // LDS broadcast
            a.x = fmaf(v, w[u].x, a.x);
            a.y = fmaf(v, w[u].y, a.y);
            a.z = fmaf(v, w[u].z, a.z);
            a.w = fmaf(v, w[u].w, a.w);
        }
        *(float4*)(&pls[kseg][n][c0]) = a;
    }
    __syncthreads();

    {   // reduce: thread = (n = t>>7, c = t&127)
        const int n = t >> 7;
        const int c = t & 127;
        float s = 0.f;
        #pragma unroll
        for (int seg = 0; seg < 16; ++seg) s += pls[seg][n][c];
        float* op;
        if (g == 0)      { op = P;   s += be1[c]; }
        else if (g == 1) { op = Q;   s += (mask[node0 + n] - 1.0f) * 1e30f; }
        else             { op = pre; s += bn1[c]; }
        op[(size_t)(node0 + n) * H_ + c] = s;
    }
}

// ---------------------------------------------------------------------------
// k2bc: fused edge loop + node epilogue. grid 512 (4 i/block), block 512.
// Edge: S'[i][c] = (m_i/max(cnt,1)) * sum_j silu(P[i][c]+Q'[j][c]+d_ij*wd[c])
//   (LDS-staged Q chunks, one acc/thread — R7 structure, ~trans-pipe floor).
// Epilogue (split-K GEMMs, S' stays in LDS):
//   T      = S' @ We2 + m_i*be2
//   hidden = silu(pre + T @ Wn1[128:])
//   out    = node + m_i * (hidden @ Wn2 + bn2)
// arena LDS (32 KB) aliases Qs (edge) and pls (epilogue partials).
// ---------------------------------------------------------------------------
__global__ __launch_bounds__(512) void k2bc(
    const float* __restrict__ P, const float* __restrict__ Q,
    const float* __restrict__ We1, const float* __restrict__ positions,
    const float* __restrict__ mask, const float* __restrict__ pre,
    const float* __restrict__ node,
    const float* __restrict__ We2, const float* __restrict__ be2,
    const float* __restrict__ Wn1, const float* __restrict__ Wn2,
    const float* __restrict__ bn2, float* __restrict__ out)
{
    __shared__ float arena[8192];     // 32 KB: Qs (edge) | pls[16][4][128] (epi)
    __shared__ float dls[256][4];
    __shared__ float Sls[4][128];
    __shared__ float Tls[4][128];
    __shared__ float cs;
    const int t  = threadIdx.x;
    const int b  = blockIdx.x >> 6;
    const int i0 = (blockIdx.x & 63) * 4;

    // pairwise distances for this block's 4 i-rows
    {
        const int t2 = t & 255;
        const int half = t >> 8;
        const int il = t2 & 3;
        const int jb = t2 >> 2;
        const float* pb = positions + b * N_ * 3;
        const float pix = pb[(i0 + il) * 3 + 0];
        const float piy = pb[(i0 + il) * 3 + 1];
        const float piz = pb[(i0 + il) * 3 + 2];
        #pragma unroll
        for (int s = 0; s < 2; ++s) {
            int j = jb + 64 * (half * 2 + s);
            float dx = pix - pb[j * 3 + 0];
            float dy = piy - pb[j * 3 + 1];
            float dz = piz - pb[j * 3 + 2];
            float sq = dx * dx + dy * dy + dz * dz;
            dls[j][il] = (sq > 0.f) ? sqrtf(sq) : 0.f;
        }
    }
    if (t < 64) {   // cnt = sum_j mask[b][j]
        float mv = mask[b * N_ + t] + mask[b * N_ + 64 + t]
                 + mask[b * N_ + 128 + t] + mask[b * N_ + 192 + t];
        #pragma unroll
        for (int off = 32; off >= 1; off >>= 1) mv += __shfl_down(mv, off);
        if (t == 0) cs = mv;
    }

    const int i = t >> 7;             // wave-uniform
    const int c = t & 127;
    const float wd   = We1[256 * H_ + c];
    const float base = P[(size_t)(b * N_ + i0 + i) * H_ + c];
    const float4* __restrict__ Qg = (const float4*)(Q + (size_t)(b * N_) * H_);

    // prefetch chunk 0 (4 float4/thread = one 32 KB chunk/block)
    float4 r0 = Qg[0 * 512 + t];
    float4 r1 = Qg[1 * 512 + t];
    float4 r2 = Qg[2 * 512 + t];
    float4 r3 = Qg[3 * 512 + t];

    float acc = 0.f;
    for (int ch = 0; ch < 4; ++ch) {
        __syncthreads();              // previous chunk's compute done
        ((float4*)arena)[0 * 512 + t] = r0;
        ((float4*)arena)[1 * 512 + t] = r1;
        ((float4*)arena)[2 * 512 + t] = r2;
        ((float4*)arena)[3 * 512 + t] = r3;
        if (ch < 3) {                 // prefetch next chunk during compute
            r0 = Qg[(ch + 1) * 2048 + 0 * 512 + t];
            r1 = Qg[(ch + 1) * 2048 + 1 * 512 + t];
            r2 = Qg[(ch + 1) * 2048 + 2 * 512 + t];
            r3 = Qg[(ch + 1) * 2048 + 3 * 512 + t];
        }
        __syncthreads();              // staging visible
        const int j0 = ch * 64;
        #pragma unroll 8
        for (int jj = 0; jj < 64; ++jj) {
            float q = arena[jj * 128 + c];
            float d = dls[j0 + jj][i];
            float x = fmaf(d, wd, base + q);
            float e = __expf(-x);
            float r = __builtin_amdgcn_rcpf(1.0f + e);
            acc = fmaf(x, r, acc);    // masked j: x~-1e30, r=0 -> -0 (finite*0)
        }
    }

    const float inv_cnt = __builtin_amdgcn_rcpf(fmaxf(cs, 1.0f));
    const float mi = mask[b * N_ + i0 + i];
    Sls[i][c] = (mi * inv_cnt) * acc;
    __syncthreads();                  // Sls visible; arena free for pls

    // ---- epilogue: split-K GEMMs (no weight-read amplification) ----
    float (*pls)[4][128] = (float (*)[4][128])arena;
    const int kseg = t >> 5;
    const int c0   = (t & 31) * 4;

    // G1: T = S' @ We2 (+ mi*be2 in reduce)
    {
        const float* Wb = We2 + (size_t)(kseg * 8) * H_ + c0;
        float4 w[8];
        #pragma unroll
        for (int u = 0; u < 8; ++u) w[u] = *(const float4*)(Wb + u * H_);
        #pragma unroll
        for (int n = 0; n < 4; ++n) {
            float4 a = {0.f, 0.f, 0.f, 0.f};
            #pragma unroll
            for (int u = 0; u < 8; ++u) {
                float v = Sls[n][kseg * 8 + u];
                a.x = fmaf(v, w[u].x, a.x); a.y = fmaf(v, w[u].y, a.y);
                a.z = fmaf(v, w[u].z, a.z); a.w = fmaf(v, w[u].w, a.w);
            }
            *(float4*)(&pls[kseg][n][c0]) = a;
        }
    }
    __syncthreads();
    {
        float s = 0.f;
        #pragma unroll
        for (int seg = 0; seg < 16; ++seg) s += pls[seg][i][c];
        Tls[i][c] = fmaf(mi, be2[c], s);
    }
    __syncthreads();

    // G2: hidden = silu(pre + T @ Wn1[128:])
    {
        const float* Wb = Wn1 + (size_t)(128 + kseg * 8) * H_ + c0;
        float4 w[8];
        #pragma unroll
        for (int u = 0; u < 8; ++u) w[u] = *(const float4*)(Wb + u * H_);
        #pragma unroll
        for (int n = 0; n < 4; ++n) {
            float4 a = {0.f, 0.f, 0.f, 0.f};
            #pragma unroll
            for (int u = 0; u < 8; ++u) {
                float v = Tls[n][kseg * 8 + u];
                a.x = fmaf(v, w[u].x, a.x); a.y = fmaf(v, w[u].y, a.y);
                a.z = fmaf(v, w[u].z, a.z); a.w = fmaf(v, w[u].w, a.w);
            }
            *(float4*)(&pls[kseg][n][c0]) = a;
        }
    }
    __syncthreads();
    {
        float s = 0.f;
        #pragma unroll
        for (int seg = 0; seg < 16; ++seg) s += pls[seg][i][c];
        float h = silu_fast(pre[(size_t)(b * N_ + i0 + i) * H_ + c] + s);
        Sls[i][c] = h;                // reuse Sls as hidden
    }
    __syncthreads();

    // G3: out = node + mi * (hidden @ Wn2 + bn2)
    {
        const float* Wb = Wn2 + (size_t)(kseg * 8) * H_ + c0;
        float4 w[8];
        #pragma unroll
        for (int u = 0; u < 8; ++u) w[u] = *(const float4*)(Wb + u * H_);
        #pragma unroll
        for (int n = 0; n < 4; ++n) {
            float4 a = {0.f, 0.f, 0.f, 0.f};
            #pragma unroll
            for (int u = 0; u < 8; ++u) {
                float v = Sls[n][kseg * 8 + u];
                a.x = fmaf(v, w[u].x, a.x); a.y = fmaf(v, w[u].y, a.y);
                a.z = fmaf(v, w[u].z, a.z); a.w = fmaf(v, w[u].w, a.w);
            }
            *(float4*)(&pls[kseg][n][c0]) = a;
        }
    }
    __syncthreads();
    {
        float s = 0.f;
        #pragma unroll
        for (int seg = 0; seg < 16; ++seg) s += pls[seg][i][c];
        const size_t idx = (size_t)(b * N_ + i0 + i) * H_ + c;
        out[idx] = node[idx] + mi * (s + bn2[c]);
    }
}

extern "C" void kernel_launch(void* const* d_in, const int* in_sizes, int n_in,
                              void* d_out, int out_size, void* d_ws, size_t ws_size,
                              hipStream_t stream)
{
    const float* node      = (const float*)d_in[0];
    const float* positions = (const float*)d_in[1];
    const float* mask      = (const float*)d_in[2];
    const float* We1       = (const float*)d_in[3];
    const float* be1       = (const float*)d_in[4];
    const float* We2       = (const float*)d_in[5];
    const float* be2       = (const float*)d_in[6];
    const float* Wn1       = (const float*)d_in[7];
    const float* bn1       = (const float*)d_in[8];
    const float* Wn2       = (const float*)d_in[9];
    const float* bn2       = (const float*)d_in[10];
    float* out = (float*)d_out;

    const size_t SZ = (size_t)NODES_ * H_;     // 1 MB each
    float* P   = (float*)d_ws;
    float* Q   = P + SZ;
    float* pre = Q + SZ;                       // peak ws = 3 MB

    k1  <<<1536, 512, 0, stream>>>(node, We1, be1, Wn1, bn1, mask, P, Q, pre);
    k2bc<<<512,  512, 0, stream>>>(P, Q, We1, positions, mask, pre, node,
                                   We2, be2, Wn1, Wn2, bn2, out);
}